// Round 11
// baseline (323.842 us; speedup 1.0000x reference)
//
#include <hip/hip_runtime.h>

using u16 = unsigned short;
using u32 = unsigned int;
typedef __attribute__((ext_vector_type(8))) short short8;
typedef __attribute__((ext_vector_type(4))) float f32x4;

#define LOG2E 1.4426950408889634f
#define SCALE2 0.18033688011112042f  // 0.125 * log2(e)

__device__ __forceinline__ u16 f2b(float f) {  // RNE fp32->bf16
  union { float f; unsigned u; } v; v.f = f;
  unsigned r = v.u + 0x7fffu + ((v.u >> 16) & 1u);
  return (u16)(r >> 16);
}

// Raw workgroup barrier: seals this wave's LDS ops (lgkmcnt 0) but does NOT
// drain vmcnt — in-flight global loads survive the barrier (unlike __syncthreads,
// which emits s_waitcnt vmcnt(0) lgkmcnt(0) and kills cross-iteration prefetch).
// Safety: LDS ops retire in order per wave; all frag ds_reads are consumed by
// MFMAs (compiler lgkmcnt waits) before reaching the barrier.
__device__ __forceinline__ void wg_barrier() {
  asm volatile("s_waitcnt lgkmcnt(0)\n\ts_barrier" ::: "memory");
}

// ---------------- merged prep: weight pack | rope table | mask transform | layernorm ----------------
__global__ __launch_bounds__(256) void prep(const float* __restrict__ w_qkv, u16* __restrict__ wqkv_b,
                                            const float* __restrict__ in_w, u16* __restrict__ inw_b,
                                            const float* __restrict__ out_w, u16* __restrict__ outw_b,
                                            float2* __restrict__ rtab,
                                            const float* __restrict__ mask, u16* __restrict__ maskp,
                                            const float* __restrict__ x,
                                            const float* __restrict__ ln_g,
                                            const float* __restrict__ ln_b,
                                            u16* __restrict__ xn) {
  __shared__ u16 T[128 * 68];
  __shared__ float sbuf[4], ssbuf[4];
  int blk = blockIdx.x, t = threadIdx.x;
  if (blk < 7168) {            // ---- fp32 -> bf16 weight pack
    int i = blk * 256 + t;
    const float* s; u16* d; int off;
    if (i < 786432)       { s = w_qkv; d = wqkv_b; off = i; }
    else if (i < 1572864) { s = in_w;  d = inw_b;  off = i - 786432; }
    else                  { s = out_w; d = outw_b; off = i - 1572864; }
    float4 v = ((const float4*)s)[off];
    uint2 o;
    o.x = (unsigned)f2b(v.x) | ((unsigned)f2b(v.y) << 16);
    o.y = (unsigned)f2b(v.z) | ((unsigned)f2b(v.w) << 16);
    ((uint2*)d)[off] = o;
  } else if (blk < 11264) {    // ---- RoPE cos/sin table
    int idx = (blk - 7168) * 256 + t;   // 1048576
    int pos = idx >> 9, i = idx & 511;
    float ifreq = exp2f(-(float)(2 * i) * (13.287712379549449f / 1024.0f));
    float ang = (float)pos * ifreq;
    rtab[idx] = make_float2(__cosf(ang), __sinf(ang));
  } else if (blk < 12288) {    // ---- mask -> bf16*log2e in S^T fragment order
    int mb = blk - 11264;      // 0..1023
    int kt = mb & 31, qt = (mb >> 5) & 15, bb = mb >> 9;
    const float* src = mask + ((size_t)bb * 2048 + qt * 128) * 2048 + kt * 64;
    #pragma unroll
    for (int it = 0; it < 8; it++) {
      int id = it * 256 + t;            // 0..2047 float4 groups (128 x 16)
      int r = id >> 4, c4 = (id & 15) * 4;
      float4 v = *(const float4*)(src + (size_t)r * 2048 + c4);
      T[r * 68 + c4 + 0] = f2b(v.x * LOG2E);
      T[r * 68 + c4 + 1] = f2b(v.y * LOG2E);
      T[r * 68 + c4 + 2] = f2b(v.z * LOG2E);
      T[r * 68 + c4 + 3] = f2b(v.w * LOG2E);
    }
    __syncthreads();
    size_t obase = (size_t)(((bb * 16 + qt) * 32) + kt) * 8192;
    #pragma unroll
    for (int it = 0; it < 2; it++) {
      int pos = it * 256 + t;           // 0..511
      int l15 = pos & 15, g = pos >> 4;
      int w = g >> 3, p = (g >> 2) & 1, qd = g & 3;
      int qlocal = w * 32 + p * 16 + l15;
      u16 vals[16];
      #pragma unroll
      for (int mt = 0; mt < 4; mt++)
        #pragma unroll
        for (int reg = 0; reg < 4; reg++)
          vals[mt * 4 + reg] = T[qlocal * 68 + mt * 16 + qd * 4 + reg];
      uint4* dst = (uint4*)(maskp + obase + (size_t)pos * 16);
      dst[0] = *(uint4*)&vals[0];
      dst[1] = *(uint4*)&vals[8];
    }
  } else {                     // ---- LayerNorm rows 0..4095 -> bf16
    int row = blk - 12288;
    const float* xr = x + (size_t)row * 1024;
    float4 v = *(const float4*)(xr + t * 4);
    float s = v.x + v.y + v.z + v.w;
    float ss = v.x * v.x + v.y * v.y + v.z * v.z + v.w * v.w;
    #pragma unroll
    for (int m = 1; m < 64; m <<= 1) {
      s  += __shfl_xor(s, m);
      ss += __shfl_xor(ss, m);
    }
    int wave = t >> 6, lane = t & 63;
    if (lane == 0) { sbuf[wave] = s; ssbuf[wave] = ss; }
    __syncthreads();
    s  = sbuf[0] + sbuf[1] + sbuf[2] + sbuf[3];
    ss = ssbuf[0] + ssbuf[1] + ssbuf[2] + ssbuf[3];
    float mean = s * (1.0f / 1024.0f);
    float var  = ss * (1.0f / 1024.0f) - mean * mean;
    float rstd = 1.0f / sqrtf(var + 1e-5f);
    float4 gv = *(const float4*)(ln_g + t * 4);
    float4 bv = *(const float4*)(ln_b + t * 4);
    uint2 o;
    o.x = (unsigned)f2b((v.x - mean) * rstd * gv.x + bv.x) |
          ((unsigned)f2b((v.y - mean) * rstd * gv.y + bv.y) << 16);
    o.y = (unsigned)f2b((v.z - mean) * rstd * gv.z + bv.z) |
          ((unsigned)f2b((v.w - mean) * rstd * gv.w + bv.w) << 16);
    *(uint2*)(xn + (size_t)row * 1024 + t * 4) = o;
  }
}

// ======== GEMM: dbuf stride-72 LDS, distance-2 scalar-VGPR pipeline, RAW barrier ========
// iter k: LSTORE(k+1 -> buf (k+1)&1)  [vmcnt wait for GLOAD(k+1) lands HERE, ~1 iter after issue]
//         GLOAD(k+2)                  [stays in flight across the raw barrier]
//         compute(buf k&1)
//         wg_barrier (lgkmcnt only — no vmcnt drain)
template<bool SLAB, bool OUT_BF16, bool ROPE>
__global__ __launch_bounds__(256, 2) void gemm_pipe(const u16* __restrict__ A, int lda,
                                                    const u16* __restrict__ W,
                                                    const float* __restrict__ bias,
                                                    const float2* __restrict__ rtab,
                                                    float* __restrict__ Cf,
                                                    u16* __restrict__ Cb,
                                                    int ldc, int K) {
  __shared__ u16 As[2][128 * 72];
  __shared__ u16 Bs[2][128 * 72];
  int n0 = blockIdx.x * 128, m0 = blockIdx.y * 128;
  int aoff = SLAB ? ((n0 >> 10) << 10) : 0;
  int tid = threadIdx.x;
  int lane = tid & 63, l15 = lane & 15, quad = lane >> 4;
  int w = tid >> 6, mw = w & 1, nw = w >> 1;
  const u16* Abase = A + (size_t)m0 * lda + aoff;
  const u16* Wbase = W + (size_t)n0 * K;
  int r0 = tid >> 3;              // 0..31
  int c8 = (tid & 7) * 8;         // col within 64-wide tile
  f32x4 acc[4][4];
  #pragma unroll
  for (int i = 0; i < 4; i++)
    #pragma unroll
    for (int j = 0; j < 4; j++) acc[i][j] = (f32x4){0.f, 0.f, 0.f, 0.f};

  uint4 a0, a1, a2, a3, w0, w1, w2, w3;
  #define GLOADS(k0)                                                          \
    a0 = *(const uint4*)(Abase + (size_t)(r0)      * lda + (k0) + c8);        \
    a1 = *(const uint4*)(Abase + (size_t)(r0 + 32) * lda + (k0) + c8);        \
    a2 = *(const uint4*)(Abase + (size_t)(r0 + 64) * lda + (k0) + c8);        \
    a3 = *(const uint4*)(Abase + (size_t)(r0 + 96) * lda + (k0) + c8);        \
    w0 = *(const uint4*)(Wbase + (size_t)(r0)      * K   + (k0) + c8);        \
    w1 = *(const uint4*)(Wbase + (size_t)(r0 + 32) * K   + (k0) + c8);        \
    w2 = *(const uint4*)(Wbase + (size_t)(r0 + 64) * K   + (k0) + c8);        \
    w3 = *(const uint4*)(Wbase + (size_t)(r0 + 96) * K   + (k0) + c8);
  #define LSTORES(b)                                                          \
    *(uint4*)&As[b][(r0)      * 72 + c8] = a0;                                \
    *(uint4*)&As[b][(r0 + 32) * 72 + c8] = a1;                                \
    *(uint4*)&As[b][(r0 + 64) * 72 + c8] = a2;                                \
    *(uint4*)&As[b][(r0 + 96) * 72 + c8] = a3;                                \
    *(uint4*)&Bs[b][(r0)      * 72 + c8] = w0;                                \
    *(uint4*)&Bs[b][(r0 + 32) * 72 + c8] = w1;                                \
    *(uint4*)&Bs[b][(r0 + 64) * 72 + c8] = w2;                                \
    *(uint4*)&Bs[b][(r0 + 96) * 72 + c8] = w3;

  GLOADS(0);
  LSTORES(0);
  if (K > 64) { GLOADS(64); }        // tile 1 in regs; stays in flight past barrier
  wg_barrier();
  for (int k0 = 0; k0 < K; k0 += 64) {
    int b = (k0 >> 6) & 1;
    if (k0 + 64 < K)  { LSTORES(b ^ 1); }    // store tile k+1 (loaded ~1 iter ago)
    if (k0 + 128 < K) { GLOADS(k0 + 128); }  // load tile k+2
    #pragma unroll
    for (int kk = 0; kk < 64; kk += 32) {
      short8 af[4], bfr[4];
      #pragma unroll
      for (int mt = 0; mt < 4; mt++)
        af[mt] = *(const short8*)&As[b][(mw * 64 + mt * 16 + l15) * 72 + kk + quad * 8];
      #pragma unroll
      for (int nt = 0; nt < 4; nt++)
        bfr[nt] = *(const short8*)&Bs[b][(nw * 64 + nt * 16 + l15) * 72 + kk + quad * 8];
      #pragma unroll
      for (int mt = 0; mt < 4; mt++)
        #pragma unroll
        for (int nt = 0; nt < 4; nt++)
          acc[mt][nt] = __builtin_amdgcn_mfma_f32_16x16x32_bf16(
              af[mt], bfr[nt], acc[mt][nt], 0, 0, 0);
    }
    wg_barrier();
  }
  #undef GLOADS
  #undef LSTORES
  int mb = m0 + mw * 64, nb = n0 + nw * 64;
  float bv[4];
  #pragma unroll
  for (int nt = 0; nt < 4; nt++) bv[nt] = bias[nb + nt * 16 + l15];
  #pragma unroll
  for (int mt = 0; mt < 4; mt++)
    #pragma unroll
    for (int nt = 0; nt < 4; nt++) {
      int col = nb + nt * 16 + l15;
      #pragma unroll
      for (int reg = 0; reg < 4; reg++) {
        int row = mb + mt * 16 + quad * 4 + reg;   // C/D: row=quad*4+reg, col=l15
        float val = acc[mt][nt][reg] + bv[nt];
        if (ROPE && col < 2048) {
          float pr = __shfl_xor(val, 1);
          float2 cs = rtab[(size_t)(row & 2047) * 512 + ((col & 1023) >> 1)];
          val = (col & 1) ? fmaf(val, cs.x, pr * cs.y)
                          : fmaf(val, cs.x, -pr * cs.y);
        }
        if (OUT_BF16) Cb[(size_t)row * ldc + col] = f2b(val);
        else          Cf[(size_t)row * ldc + col] = val;
      }
    }
}

// ---------------- V transpose: qkv2 v-cols -> vT[bb][h][d][s] bf16 ----------------
__global__ __launch_bounds__(256) void transpose_v(const u16* __restrict__ qkv2,
                                                   u16* __restrict__ vT) {
  __shared__ u16 T[64 * 72];
  int st = blockIdx.x, h = blockIdx.y, bb = blockIdx.z;
  int t = threadIdx.x;
  int r = t >> 2, c0 = (t & 3) * 16;
  const u16* src = qkv2 + (size_t)(bb * 2048 + st * 64 + r) * 3072 + 2048 + h * 64 + c0;
  *(uint4*)&T[r * 72 + c0]     = *(const uint4*)src;
  *(uint4*)&T[r * 72 + c0 + 8] = *(const uint4*)(src + 8);
  __syncthreads();
  int d = t >> 2, s0 = (t & 3) * 16;
  u16 tmp[16];
  #pragma unroll
  for (int j = 0; j < 16; j++) tmp[j] = T[(s0 + j) * 72 + d];
  u16* dst = vT + ((size_t)((bb * 16 + h) * 64 + d)) * 2048 + st * 64 + s0;
  *(uint4*)dst       = *(uint4*)&tmp[0];
  *(uint4*)(dst + 8) = *(uint4*)&tmp[8];
}

// ---------------- Flash attention: MQ=128, S^T formulation, raw barrier ----------------
__global__ __launch_bounds__(256) void attn_mfma(const u16* __restrict__ qkv2,
                                                 const u16* __restrict__ vT,
                                                 const u16* __restrict__ maskp,
                                                 u16* __restrict__ attn_out) {
  __shared__ u16 Kb[2][64 * 72];
  __shared__ u16 Vb[2][64 * 72];
  __shared__ u16 Ps[128 * 72];
  int h = blockIdx.x, qt = blockIdx.y, bb = blockIdx.z;
  int tid = threadIdx.x;
  int lane = tid & 63, l15 = lane & 15, quad = lane >> 4;
  int w = tid >> 6;
  int sr = tid >> 2, sc = (tid & 3) * 16;   // K/V staging decomposition (64x64 tile)
  const u16* kslab = qkv2 + ((size_t)bb * 2048) * 3072 + 1024 + h * 64;
  const u16* vslab = vT + ((size_t)((bb * 16 + h) * 64)) * 2048;

  {  // stage Q into wave-local Ps rows [w*32, w*32+32)
    int r = w * 32 + (lane >> 1), c0 = (lane & 1) * 32;
    const u16* src = qkv2 + (size_t)(bb * 2048 + qt * 128 + r) * 3072 + h * 64 + c0;
    #pragma unroll
    for (int u = 0; u < 4; u++)
      *(uint4*)&Ps[r * 72 + c0 + u * 8] = *(const uint4*)(src + u * 8);
  }
  {  // stage K/V tile 0
    const u16* ks = kslab + (size_t)sr * 3072 + sc;
    const u16* vs = vslab + (size_t)sr * 2048 + sc;
    *(uint4*)&Kb[0][sr * 72 + sc]     = *(const uint4*)ks;
    *(uint4*)&Kb[0][sr * 72 + sc + 8] = *(const uint4*)(ks + 8);
    *(uint4*)&Vb[0][sr * 72 + sc]     = *(const uint4*)vs;
    *(uint4*)&Vb[0][sr * 72 + sc + 8] = *(const uint4*)(vs + 8);
  }
  short8 bq[2][2];
  #pragma unroll
  for (int p = 0; p < 2; p++)
    #pragma unroll
    for (int hk = 0; hk < 2; hk++)
      bq[p][hk] = *(const short8*)&Ps[(w * 32 + p * 16 + l15) * 72 + hk * 32 + quad * 8];
  float lsum[2] = {0.f, 0.f};
  f32x4 acc[2][4];
  #pragma unroll
  for (int p = 0; p < 2; p++)
    #pragma unroll
    for (int dt = 0; dt < 4; dt++) acc[p][dt] = (f32x4){0.f, 0.f, 0.f, 0.f};
  const u16* mtile = maskp + ((size_t)((bb * 16 + qt) * 32)) * 8192
                     + (((w * 2) * 4 + quad) * 16 + l15) * 16;
  wg_barrier();

  for (int kt = 0; kt < 32; kt++) {
    int b = kt & 1;
    uint4 mA[2], mB[2];
    {
      const u16* mt_ = mtile + (size_t)kt * 8192;
      #pragma unroll
      for (int p = 0; p < 2; p++) {
        const uint4* mq = (const uint4*)(mt_ + p * 1024);
        mA[p] = mq[0]; mB[p] = mq[1];
      }
    }
    uint4 kr0, kr1, vr0, vr1;
    if (kt + 1 < 32) {
      const u16* ks = kslab + (size_t)((kt + 1) * 64 + sr) * 3072 + sc;
      const u16* vs = vslab + (size_t)sr * 2048 + (kt + 1) * 64 + sc;
      kr0 = *(const uint4*)ks; kr1 = *(const uint4*)(ks + 8);
      vr0 = *(const uint4*)vs; vr1 = *(const uint4*)(vs + 8);
    }
    short8 ak[4][2];
    #pragma unroll
    for (int mt = 0; mt < 4; mt++)
      #pragma unroll
      for (int hk = 0; hk < 2; hk++)
        ak[mt][hk] = *(const short8*)&Kb[b][(mt * 16 + l15) * 72 + hk * 32 + quad * 8];
    #pragma unroll
    for (int p = 0; p < 2; p++) {
      f32x4 st[4];
      #pragma unroll
      for (int mt = 0; mt < 4; mt++) {
        f32x4 z = (f32x4){0.f, 0.f, 0.f, 0.f};
        z = __builtin_amdgcn_mfma_f32_16x16x32_bf16(ak[mt][0], bq[p][0], z, 0, 0, 0);
        st[mt] = __builtin_amdgcn_mfma_f32_16x16x32_bf16(ak[mt][1], bq[p][1], z, 0, 0, 0);
      }
      u32 wds[8] = {mA[p].x, mA[p].y, mA[p].z, mA[p].w, mB[p].x, mB[p].y, mB[p].z, mB[p].w};
      float mv[16];
      #pragma unroll
      for (int j = 0; j < 8; j++) {
        mv[2 * j]     = __uint_as_float(wds[j] << 16);
        mv[2 * j + 1] = __uint_as_float(wds[j] & 0xffff0000u);
      }
      int prow = (w * 32 + p * 16 + l15) * 72 + quad * 4;
      #pragma unroll
      for (int mt = 0; mt < 4; mt++) {
        u32 pk0, pk1;
        float sv0 = fmaf(st[mt][0], SCALE2, mv[mt * 4 + 0]);
        float sv1 = fmaf(st[mt][1], SCALE2, mv[mt * 4 + 1]);
        float sv2 = fmaf(st[mt][2], SCALE2, mv[mt * 4 + 2]);
        float sv3 = fmaf(st[mt][3], SCALE2, mv[mt * 4 + 3]);
        float p0 = __builtin_amdgcn_exp2f(sv0), p1 = __builtin_amdgcn_exp2f(sv1);
        float p2 = __builtin_amdgcn_exp2f(sv2), p3 = __builtin_amdgcn_exp2f(sv3);
        lsum[p] += (p0 + p1) + (p2 + p3);
        pk0 = ((__float_as_uint(p0) + 0x8000u) >> 16) |
              ((__float_as_uint(p1) + 0x8000u) & 0xffff0000u);
        pk1 = ((__float_as_uint(p2) + 0x8000u) >> 16) |
              ((__float_as_uint(p3) + 0x8000u) & 0xffff0000u);
        *(uint2*)&Ps[prow + mt * 16] = make_uint2(pk0, pk1);
      }
    }
    short8 ap[2][2];
    #pragma unroll
    for (int p = 0; p < 2; p++)
      #pragma unroll
      for (int hk = 0; hk < 2; hk++)
        ap[p][hk] = *(const short8*)&Ps[(w * 32 + p * 16 + l15) * 72 + hk * 32 + quad * 8];
    #pragma unroll
    for (int dt = 0; dt < 4; dt++) {
      short8 bv0 = *(const short8*)&Vb[b][(dt * 16 + l15) * 72 + quad * 8];
      short8 bv1 = *(const short8*)&Vb[b][(dt * 16 + l15) * 72 + 32 + quad * 8];
      #pragma unroll
      for (int p = 0; p < 2; p++) {
        acc[p][dt] = __builtin_amdgcn_mfma_f32_16x16x32_bf16(ap[p][0], bv0, acc[p][dt], 0, 0, 0);
        acc[p][dt] = __builtin_amdgcn_mfma_f32_16x16x32_bf16(ap[p][1], bv1, acc[p][dt], 0, 0, 0);
      }
    }
    if (kt + 1 < 32) {
      int nb = b ^ 1;
      *(uint4*)&Kb[nb][sr * 72 + sc]     = kr0;
      *(uint4*)&Kb[nb][sr * 72 + sc + 8] = kr1;
      *(uint4*)&Vb[nb][sr * 72 + sc]     = vr0;
      *(uint4*)&Vb[nb][sr * 72 + sc + 8] = vr1;
    }
    wg_barrier();
  }
  #pragma unroll
  for (int p = 0; p < 2; p++) {
    float l = lsum[p];
    l += __shfl_xor(l, 16);
    l += __shfl_xor(l, 32);
    #pragma unroll
    for (int reg = 0; reg < 4; reg++) {
      float lq = __shfl(l, quad * 4 + reg);
      float inv = 1.0f / lq;
      int grow = bb * 2048 + qt * 128 + w * 32 + p * 16 + quad * 4 + reg;
      #pragma unroll
      for (int dt = 0; dt < 4; dt++)
        attn_out[(size_t)grow * 1024 + h * 64 + dt * 16 + l15] = f2b(acc[p][dt][reg] * inv);
    }
  }
}

extern "C" void kernel_launch(void* const* d_in, const int* in_sizes, int n_in,
                              void* d_out, int out_size, void* d_ws, size_t ws_size,
                              hipStream_t stream) {
  const float* x     = (const float*)d_in[0];
  const float* mask  = (const float*)d_in[1];
  const float* ln_g  = (const float*)d_in[2];
  const float* ln_b  = (const float*)d_in[3];
  const float* w_qkv = (const float*)d_in[4];
  const float* b_qkv = (const float*)d_in[5];
  const float* in_w  = (const float*)d_in[6];
  const float* in_b  = (const float*)d_in[7];
  const float* out_w = (const float*)d_in[8];
  const float* out_b = (const float*)d_in[9];
  float* out = (float*)d_out;
  char* ws = (char*)d_ws;

  u16* wqkv_b = (u16*)(ws);                   //  6291456  (3072x1024)
  u16* inw_b  = (u16*)(ws + 6291456ull);      //  6291456  (3072x1024)
  u16* outw_b = (u16*)(ws + 12582912ull);     //  2097152  (1024x1024)
  u16* xn_b   = (u16*)(ws + 14680064ull);     //  8388608  (4096x1024)
  u16* attn_b = xn_b;                         //  reuse (xn dead after gemm1)
  u16* qkv_b  = (u16*)(ws + 23068672ull);     // 25165824  (4096x3072)
  u16* qkv2_b = (u16*)(ws + 48234496ull);     // 25165824  (4096x3072)
  float2* rtab = (float2*)qkv2_b;             //  8388608  aliases qkv2 (dead before gemm2)
  u16* vT     = (u16*)(ws + 73400320ull);     //  8388608  (2,16,64,2048)
  u16* maskp  = (u16*)(ws + 81788928ull);     // 16777216  (2*16*32 tiles * 8192 u16)

  prep<<<16384, 256, 0, stream>>>(w_qkv, wqkv_b, in_w, inw_b, out_w, outw_b,
                                  rtab, mask, maskp, x, ln_g, ln_b, xn_b);
  gemm_pipe<false, true, true><<<dim3(24, 32), 256, 0, stream>>>(
      xn_b, 1024, wqkv_b, b_qkv, rtab, nullptr, qkv_b, 3072, 1024);
  gemm_pipe<true, true, false><<<dim3(24, 32), 256, 0, stream>>>(
      qkv_b, 3072, inw_b, in_b, nullptr, nullptr, qkv2_b, 3072, 1024);
  transpose_v<<<dim3(32, 16, 2), 256, 0, stream>>>(qkv2_b, vT);
  attn_mfma<<<dim3(16, 16, 2), 256, 0, stream>>>(qkv2_b, vT, maskp, attn_b);
  gemm_pipe<false, false, false><<<dim3(8, 32), 256, 0, stream>>>(
      attn_b, 1024, outw_b, out_b, nullptr, out, nullptr, 1024, 1024);
}

// Round 12
// 310.554 us; speedup vs baseline: 1.0428x; 1.0428x over previous
//
#include <hip/hip_runtime.h>

using u16 = unsigned short;
using u32 = unsigned int;
typedef __attribute__((ext_vector_type(8))) short short8;
typedef __attribute__((ext_vector_type(4))) float f32x4;

#define LOG2E 1.4426950408889634f
#define SCALE2 0.18033688011112042f  // 0.125 * log2(e)

__device__ __forceinline__ u16 f2b(float f) {  // RNE fp32->bf16
  union { float f; unsigned u; } v; v.f = f;
  unsigned r = v.u + 0x7fffu + ((v.u >> 16) & 1u);
  return (u16)(r >> 16);
}

// Raw workgroup barrier: seals LDS ops (lgkmcnt 0), avoids forcing vmcnt drain
// at source level (whether the waitcnt pass still drains is moot — neutral R11).
__device__ __forceinline__ void wg_barrier() {
  asm volatile("s_waitcnt lgkmcnt(0)\n\ts_barrier" ::: "memory");
}

// ---------------- merged prep: weight pack | rope table | mask transform | layernorm ----------------
__global__ __launch_bounds__(256) void prep(const float* __restrict__ w_qkv, u16* __restrict__ wqkv_b,
                                            const float* __restrict__ in_w, u16* __restrict__ inw_b,
                                            const float* __restrict__ out_w, u16* __restrict__ outw_b,
                                            float2* __restrict__ rtab,
                                            const float* __restrict__ mask, u16* __restrict__ maskp,
                                            const float* __restrict__ x,
                                            const float* __restrict__ ln_g,
                                            const float* __restrict__ ln_b,
                                            u16* __restrict__ xn) {
  __shared__ u16 T[128 * 68];
  __shared__ float sbuf[4], ssbuf[4];
  int blk = blockIdx.x, t = threadIdx.x;
  if (blk < 7168) {            // ---- fp32 -> bf16 weight pack
    int i = blk * 256 + t;
    const float* s; u16* d; int off;
    if (i < 786432)       { s = w_qkv; d = wqkv_b; off = i; }
    else if (i < 1572864) { s = in_w;  d = inw_b;  off = i - 786432; }
    else                  { s = out_w; d = outw_b; off = i - 1572864; }
    float4 v = ((const float4*)s)[off];
    uint2 o;
    o.x = (unsigned)f2b(v.x) | ((unsigned)f2b(v.y) << 16);
    o.y = (unsigned)f2b(v.z) | ((unsigned)f2b(v.w) << 16);
    ((uint2*)d)[off] = o;
  } else if (blk < 11264) {    // ---- RoPE cos/sin table
    int idx = (blk - 7168) * 256 + t;   // 1048576
    int pos = idx >> 9, i = idx & 511;
    float ifreq = exp2f(-(float)(2 * i) * (13.287712379549449f / 1024.0f));
    float ang = (float)pos * ifreq;
    rtab[idx] = make_float2(__cosf(ang), __sinf(ang));
  } else if (blk < 12288) {    // ---- mask -> bf16*log2e in S^T fragment order
    int mb = blk - 11264;      // 0..1023
    int kt = mb & 31, qt = (mb >> 5) & 15, bb = mb >> 9;
    const float* src = mask + ((size_t)bb * 2048 + qt * 128) * 2048 + kt * 64;
    #pragma unroll
    for (int it = 0; it < 8; it++) {
      int id = it * 256 + t;            // 0..2047 float4 groups (128 x 16)
      int r = id >> 4, c4 = (id & 15) * 4;
      float4 v = *(const float4*)(src + (size_t)r * 2048 + c4);
      T[r * 68 + c4 + 0] = f2b(v.x * LOG2E);
      T[r * 68 + c4 + 1] = f2b(v.y * LOG2E);
      T[r * 68 + c4 + 2] = f2b(v.z * LOG2E);
      T[r * 68 + c4 + 3] = f2b(v.w * LOG2E);
    }
    __syncthreads();
    size_t obase = (size_t)(((bb * 16 + qt) * 32) + kt) * 8192;
    #pragma unroll
    for (int it = 0; it < 2; it++) {
      int pos = it * 256 + t;           // 0..511
      int l15 = pos & 15, g = pos >> 4;
      int w = g >> 3, p = (g >> 2) & 1, qd = g & 3;
      int qlocal = w * 32 + p * 16 + l15;
      u16 vals[16];
      #pragma unroll
      for (int mt = 0; mt < 4; mt++)
        #pragma unroll
        for (int reg = 0; reg < 4; reg++)
          vals[mt * 4 + reg] = T[qlocal * 68 + mt * 16 + qd * 4 + reg];
      uint4* dst = (uint4*)(maskp + obase + (size_t)pos * 16);
      dst[0] = *(uint4*)&vals[0];
      dst[1] = *(uint4*)&vals[8];
    }
  } else {                     // ---- LayerNorm rows 0..4095 -> bf16
    int row = blk - 12288;
    const float* xr = x + (size_t)row * 1024;
    float4 v = *(const float4*)(xr + t * 4);
    float s = v.x + v.y + v.z + v.w;
    float ss = v.x * v.x + v.y * v.y + v.z * v.z + v.w * v.w;
    #pragma unroll
    for (int m = 1; m < 64; m <<= 1) {
      s  += __shfl_xor(s, m);
      ss += __shfl_xor(ss, m);
    }
    int wave = t >> 6, lane = t & 63;
    if (lane == 0) { sbuf[wave] = s; ssbuf[wave] = ss; }
    __syncthreads();
    s  = sbuf[0] + sbuf[1] + sbuf[2] + sbuf[3];
    ss = ssbuf[0] + ssbuf[1] + ssbuf[2] + ssbuf[3];
    float mean = s * (1.0f / 1024.0f);
    float var  = ss * (1.0f / 1024.0f) - mean * mean;
    float rstd = 1.0f / sqrtf(var + 1e-5f);
    float4 gv = *(const float4*)(ln_g + t * 4);
    float4 bv = *(const float4*)(ln_b + t * 4);
    uint2 o;
    o.x = (unsigned)f2b((v.x - mean) * rstd * gv.x + bv.x) |
          ((unsigned)f2b((v.y - mean) * rstd * gv.y + bv.y) << 16);
    o.y = (unsigned)f2b((v.z - mean) * rstd * gv.z + bv.z) |
          ((unsigned)f2b((v.w - mean) * rstd * gv.w + bv.w) << 16);
    *(uint2*)(xn + (size_t)row * 1024 + t * 4) = o;
  }
}

// ======== GEMM: BK=32, dbuf stride-36 LDS (36KB -> 3 blocks/CU, one dispatch
// generation for 768 blocks), distance-2 scalar-VGPR pipeline, raw barrier ========
template<bool SLAB, bool OUT_BF16, bool ROPE>
__global__ __launch_bounds__(256, 3) void gemm_pipe(const u16* __restrict__ A, int lda,
                                                    const u16* __restrict__ W,
                                                    const float* __restrict__ bias,
                                                    const float2* __restrict__ rtab,
                                                    float* __restrict__ Cf,
                                                    u16* __restrict__ Cb,
                                                    int ldc, int K) {
  __shared__ u16 As[2][128 * 36];
  __shared__ u16 Bs[2][128 * 36];
  int n0 = blockIdx.x * 128, m0 = blockIdx.y * 128;
  int aoff = SLAB ? ((n0 >> 10) << 10) : 0;
  int tid = threadIdx.x;
  int lane = tid & 63, l15 = lane & 15, quad = lane >> 4;
  int w = tid >> 6, mw = w & 1, nw = w >> 1;
  const u16* Abase = A + (size_t)m0 * lda + aoff;
  const u16* Wbase = W + (size_t)n0 * K;
  int r0 = tid >> 2;              // 0..63
  int c4 = (tid & 3) * 8;         // col within 32-wide tile
  f32x4 acc[4][4];
  #pragma unroll
  for (int i = 0; i < 4; i++)
    #pragma unroll
    for (int j = 0; j < 4; j++) acc[i][j] = (f32x4){0.f, 0.f, 0.f, 0.f};

  uint4 a0, a1, w0, w1;
  #define GLOADS(k0)                                                          \
    a0 = *(const uint4*)(Abase + (size_t)(r0)      * lda + (k0) + c4);        \
    a1 = *(const uint4*)(Abase + (size_t)(r0 + 64) * lda + (k0) + c4);        \
    w0 = *(const uint4*)(Wbase + (size_t)(r0)      * K   + (k0) + c4);        \
    w1 = *(const uint4*)(Wbase + (size_t)(r0 + 64) * K   + (k0) + c4);
  #define LSTORES(b)                                                          \
    *(uint4*)&As[b][(r0)      * 36 + c4] = a0;                                \
    *(uint4*)&As[b][(r0 + 64) * 36 + c4] = a1;                                \
    *(uint4*)&Bs[b][(r0)      * 36 + c4] = w0;                                \
    *(uint4*)&Bs[b][(r0 + 64) * 36 + c4] = w1;

  GLOADS(0);
  LSTORES(0);
  if (K > 32) { GLOADS(32); }        // tile 1 in regs
  wg_barrier();
  for (int k0 = 0; k0 < K; k0 += 32) {
    int b = (k0 >> 5) & 1;
    if (k0 + 32 < K) { LSTORES(b ^ 1); }    // store tile k+1 (loaded ~1 iter ago)
    if (k0 + 64 < K) { GLOADS(k0 + 64); }   // load tile k+2
    short8 af[4], bfr[4];
    #pragma unroll
    for (int mt = 0; mt < 4; mt++)
      af[mt] = *(const short8*)&As[b][(mw * 64 + mt * 16 + l15) * 36 + quad * 8];
    #pragma unroll
    for (int nt = 0; nt < 4; nt++)
      bfr[nt] = *(const short8*)&Bs[b][(nw * 64 + nt * 16 + l15) * 36 + quad * 8];
    #pragma unroll
    for (int mt = 0; mt < 4; mt++)
      #pragma unroll
      for (int nt = 0; nt < 4; nt++)
        acc[mt][nt] = __builtin_amdgcn_mfma_f32_16x16x32_bf16(
            af[mt], bfr[nt], acc[mt][nt], 0, 0, 0);
    wg_barrier();
  }
  #undef GLOADS
  #undef LSTORES
  int mb = m0 + mw * 64, nb = n0 + nw * 64;
  float bv[4];
  #pragma unroll
  for (int nt = 0; nt < 4; nt++) bv[nt] = bias[nb + nt * 16 + l15];
  #pragma unroll
  for (int mt = 0; mt < 4; mt++)
    #pragma unroll
    for (int nt = 0; nt < 4; nt++) {
      int col = nb + nt * 16 + l15;
      #pragma unroll
      for (int reg = 0; reg < 4; reg++) {
        int row = mb + mt * 16 + quad * 4 + reg;   // C/D: row=quad*4+reg, col=l15
        float val = acc[mt][nt][reg] + bv[nt];
        if (ROPE && col < 2048) {
          float pr = __shfl_xor(val, 1);
          float2 cs = rtab[(size_t)(row & 2047) * 512 + ((col & 1023) >> 1)];
          val = (col & 1) ? fmaf(val, cs.x, pr * cs.y)
                          : fmaf(val, cs.x, -pr * cs.y);
        }
        if (OUT_BF16) Cb[(size_t)row * ldc + col] = f2b(val);
        else          Cf[(size_t)row * ldc + col] = val;
      }
    }
}

// ---------------- V transpose: qkv2 v-cols -> vT[bb][h][d][s] bf16 ----------------
__global__ __launch_bounds__(256) void transpose_v(const u16* __restrict__ qkv2,
                                                   u16* __restrict__ vT) {
  __shared__ u16 T[64 * 72];
  int st = blockIdx.x, h = blockIdx.y, bb = blockIdx.z;
  int t = threadIdx.x;
  int r = t >> 2, c0 = (t & 3) * 16;
  const u16* src = qkv2 + (size_t)(bb * 2048 + st * 64 + r) * 3072 + 2048 + h * 64 + c0;
  *(uint4*)&T[r * 72 + c0]     = *(const uint4*)src;
  *(uint4*)&T[r * 72 + c0 + 8] = *(const uint4*)(src + 8);
  __syncthreads();
  int d = t >> 2, s0 = (t & 3) * 16;
  u16 tmp[16];
  #pragma unroll
  for (int j = 0; j < 16; j++) tmp[j] = T[(s0 + j) * 72 + d];
  u16* dst = vT + ((size_t)((bb * 16 + h) * 64 + d)) * 2048 + st * 64 + s0;
  *(uint4*)dst       = *(uint4*)&tmp[0];
  *(uint4*)(dst + 8) = *(uint4*)&tmp[8];
}

// ---------------- Flash attention: MQ=128, S^T formulation, raw barrier ----------------
__global__ __launch_bounds__(256) void attn_mfma(const u16* __restrict__ qkv2,
                                                 const u16* __restrict__ vT,
                                                 const u16* __restrict__ maskp,
                                                 u16* __restrict__ attn_out) {
  __shared__ u16 Kb[2][64 * 72];
  __shared__ u16 Vb[2][64 * 72];
  __shared__ u16 Ps[128 * 72];
  int h = blockIdx.x, qt = blockIdx.y, bb = blockIdx.z;
  int tid = threadIdx.x;
  int lane = tid & 63, l15 = lane & 15, quad = lane >> 4;
  int w = tid >> 6;
  int sr = tid >> 2, sc = (tid & 3) * 16;   // K/V staging decomposition (64x64 tile)
  const u16* kslab = qkv2 + ((size_t)bb * 2048) * 3072 + 1024 + h * 64;
  const u16* vslab = vT + ((size_t)((bb * 16 + h) * 64)) * 2048;

  {  // stage Q into wave-local Ps rows [w*32, w*32+32)
    int r = w * 32 + (lane >> 1), c0 = (lane & 1) * 32;
    const u16* src = qkv2 + (size_t)(bb * 2048 + qt * 128 + r) * 3072 + h * 64 + c0;
    #pragma unroll
    for (int u = 0; u < 4; u++)
      *(uint4*)&Ps[r * 72 + c0 + u * 8] = *(const uint4*)(src + u * 8);
  }
  {  // stage K/V tile 0
    const u16* ks = kslab + (size_t)sr * 3072 + sc;
    const u16* vs = vslab + (size_t)sr * 2048 + sc;
    *(uint4*)&Kb[0][sr * 72 + sc]     = *(const uint4*)ks;
    *(uint4*)&Kb[0][sr * 72 + sc + 8] = *(const uint4*)(ks + 8);
    *(uint4*)&Vb[0][sr * 72 + sc]     = *(const uint4*)vs;
    *(uint4*)&Vb[0][sr * 72 + sc + 8] = *(const uint4*)(vs + 8);
  }
  short8 bq[2][2];
  #pragma unroll
  for (int p = 0; p < 2; p++)
    #pragma unroll
    for (int hk = 0; hk < 2; hk++)
      bq[p][hk] = *(const short8*)&Ps[(w * 32 + p * 16 + l15) * 72 + hk * 32 + quad * 8];
  float lsum[2] = {0.f, 0.f};
  f32x4 acc[2][4];
  #pragma unroll
  for (int p = 0; p < 2; p++)
    #pragma unroll
    for (int dt = 0; dt < 4; dt++) acc[p][dt] = (f32x4){0.f, 0.f, 0.f, 0.f};
  const u16* mtile = maskp + ((size_t)((bb * 16 + qt) * 32)) * 8192
                     + (((w * 2) * 4 + quad) * 16 + l15) * 16;
  wg_barrier();

  for (int kt = 0; kt < 32; kt++) {
    int b = kt & 1;
    uint4 mA[2], mB[2];
    {
      const u16* mt_ = mtile + (size_t)kt * 8192;
      #pragma unroll
      for (int p = 0; p < 2; p++) {
        const uint4* mq = (const uint4*)(mt_ + p * 1024);
        mA[p] = mq[0]; mB[p] = mq[1];
      }
    }
    uint4 kr0, kr1, vr0, vr1;
    if (kt + 1 < 32) {
      const u16* ks = kslab + (size_t)((kt + 1) * 64 + sr) * 3072 + sc;
      const u16* vs = vslab + (size_t)sr * 2048 + (kt + 1) * 64 + sc;
      kr0 = *(const uint4*)ks; kr1 = *(const uint4*)(ks + 8);
      vr0 = *(const uint4*)vs; vr1 = *(const uint4*)(vs + 8);
    }
    short8 ak[4][2];
    #pragma unroll
    for (int mt = 0; mt < 4; mt++)
      #pragma unroll
      for (int hk = 0; hk < 2; hk++)
        ak[mt][hk] = *(const short8*)&Kb[b][(mt * 16 + l15) * 72 + hk * 32 + quad * 8];
    #pragma unroll
    for (int p = 0; p < 2; p++) {
      f32x4 st[4];
      #pragma unroll
      for (int mt = 0; mt < 4; mt++) {
        f32x4 z = (f32x4){0.f, 0.f, 0.f, 0.f};
        z = __builtin_amdgcn_mfma_f32_16x16x32_bf16(ak[mt][0], bq[p][0], z, 0, 0, 0);
        st[mt] = __builtin_amdgcn_mfma_f32_16x16x32_bf16(ak[mt][1], bq[p][1], z, 0, 0, 0);
      }
      u32 wds[8] = {mA[p].x, mA[p].y, mA[p].z, mA[p].w, mB[p].x, mB[p].y, mB[p].z, mB[p].w};
      float mv[16];
      #pragma unroll
      for (int j = 0; j < 8; j++) {
        mv[2 * j]     = __uint_as_float(wds[j] << 16);
        mv[2 * j + 1] = __uint_as_float(wds[j] & 0xffff0000u);
      }
      int prow = (w * 32 + p * 16 + l15) * 72 + quad * 4;
      #pragma unroll
      for (int mt = 0; mt < 4; mt++) {
        u32 pk0, pk1;
        float sv0 = fmaf(st[mt][0], SCALE2, mv[mt * 4 + 0]);
        float sv1 = fmaf(st[mt][1], SCALE2, mv[mt * 4 + 1]);
        float sv2 = fmaf(st[mt][2], SCALE2, mv[mt * 4 + 2]);
        float sv3 = fmaf(st[mt][3], SCALE2, mv[mt * 4 + 3]);
        float p0 = __builtin_amdgcn_exp2f(sv0), p1 = __builtin_amdgcn_exp2f(sv1);
        float p2 = __builtin_amdgcn_exp2f(sv2), p3 = __builtin_amdgcn_exp2f(sv3);
        lsum[p] += (p0 + p1) + (p2 + p3);
        pk0 = ((__float_as_uint(p0) + 0x8000u) >> 16) |
              ((__float_as_uint(p1) + 0x8000u) & 0xffff0000u);
        pk1 = ((__float_as_uint(p2) + 0x8000u) >> 16) |
              ((__float_as_uint(p3) + 0x8000u) & 0xffff0000u);
        *(uint2*)&Ps[prow + mt * 16] = make_uint2(pk0, pk1);
      }
    }
    short8 ap[2][2];
    #pragma unroll
    for (int p = 0; p < 2; p++)
      #pragma unroll
      for (int hk = 0; hk < 2; hk++)
        ap[p][hk] = *(const short8*)&Ps[(w * 32 + p * 16 + l15) * 72 + hk * 32 + quad * 8];
    #pragma unroll
    for (int dt = 0; dt < 4; dt++) {
      short8 bv0 = *(const short8*)&Vb[b][(dt * 16 + l15) * 72 + quad * 8];
      short8 bv1 = *(const short8*)&Vb[b][(dt * 16 + l15) * 72 + 32 + quad * 8];
      #pragma unroll
      for (int p = 0; p < 2; p++) {
        acc[p][dt] = __builtin_amdgcn_mfma_f32_16x16x32_bf16(ap[p][0], bv0, acc[p][dt], 0, 0, 0);
        acc[p][dt] = __builtin_amdgcn_mfma_f32_16x16x32_bf16(ap[p][1], bv1, acc[p][dt], 0, 0, 0);
      }
    }
    if (kt + 1 < 32) {
      int nb = b ^ 1;
      *(uint4*)&Kb[nb][sr * 72 + sc]     = kr0;
      *(uint4*)&Kb[nb][sr * 72 + sc + 8] = kr1;
      *(uint4*)&Vb[nb][sr * 72 + sc]     = vr0;
      *(uint4*)&Vb[nb][sr * 72 + sc + 8] = vr1;
    }
    wg_barrier();
  }
  #pragma unroll
  for (int p = 0; p < 2; p++) {
    float l = lsum[p];
    l += __shfl_xor(l, 16);
    l += __shfl_xor(l, 32);
    #pragma unroll
    for (int reg = 0; reg < 4; reg++) {
      float lq = __shfl(l, quad * 4 + reg);
      float inv = 1.0f / lq;
      int grow = bb * 2048 + qt * 128 + w * 32 + p * 16 + quad * 4 + reg;
      #pragma unroll
      for (int dt = 0; dt < 4; dt++)
        attn_out[(size_t)grow * 1024 + h * 64 + dt * 16 + l15] = f2b(acc[p][dt][reg] * inv);
    }
  }
}

extern "C" void kernel_launch(void* const* d_in, const int* in_sizes, int n_in,
                              void* d_out, int out_size, void* d_ws, size_t ws_size,
                              hipStream_t stream) {
  const float* x     = (const float*)d_in[0];
  const float* mask  = (const float*)d_in[1];
  const float* ln_g  = (const float*)d_in[2];
  const float* ln_b  = (const float*)d_in[3];
  const float* w_qkv = (const float*)d_in[4];
  const float* b_qkv = (const float*)d_in[5];
  const float* in_w  = (const float*)d_in[6];
  const float* in_b  = (const float*)d_in[7];
  const float* out_w = (const float*)d_in[8];
  const float* out_b = (const float*)d_in[9];
  float* out = (float*)d_out;
  char* ws = (char*)d_ws;

  u16* wqkv_b = (u16*)(ws);                   //  6291456  (3072x1024)
  u16* inw_b  = (u16*)(ws + 6291456ull);      //  6291456  (3072x1024)
  u16* outw_b = (u16*)(ws + 12582912ull);     //  2097152  (1024x1024)
  u16* xn_b   = (u16*)(ws + 14680064ull);     //  8388608  (4096x1024)
  u16* attn_b = xn_b;                         //  reuse (xn dead after gemm1)
  u16* qkv_b  = (u16*)(ws + 23068672ull);     // 25165824  (4096x3072)
  u16* qkv2_b = (u16*)(ws + 48234496ull);     // 25165824  (4096x3072)
  float2* rtab = (float2*)qkv2_b;             //  8388608  aliases qkv2 (dead before gemm2)
  u16* vT     = (u16*)(ws + 73400320ull);     //  8388608  (2,16,64,2048)
  u16* maskp  = (u16*)(ws + 81788928ull);     // 16777216  (2*16*32 tiles * 8192 u16)

  prep<<<16384, 256, 0, stream>>>(w_qkv, wqkv_b, in_w, inw_b, out_w, outw_b,
                                  rtab, mask, maskp, x, ln_g, ln_b, xn_b);
  gemm_pipe<false, true, true><<<dim3(24, 32), 256, 0, stream>>>(
      xn_b, 1024, wqkv_b, b_qkv, rtab, nullptr, qkv_b, 3072, 1024);
  gemm_pipe<true, true, false><<<dim3(24, 32), 256, 0, stream>>>(
      qkv_b, 3072, inw_b, in_b, nullptr, nullptr, qkv2_b, 3072, 1024);
  transpose_v<<<dim3(32, 16, 2), 256, 0, stream>>>(qkv2_b, vT);
  attn_mfma<<<dim3(16, 16, 2), 256, 0, stream>>>(qkv2_b, vT, maskp, attn_b);
  gemm_pipe<false, false, false><<<dim3(8, 32), 256, 0, stream>>>(
      attn_b, 1024, outw_b, out_b, nullptr, out, nullptr, 1024, 1024);
}

// Round 13
// 302.383 us; speedup vs baseline: 1.0710x; 1.0270x over previous
//
#include <hip/hip_runtime.h>

using u16 = unsigned short;
using u32 = unsigned int;
typedef __attribute__((ext_vector_type(8))) short short8;
typedef __attribute__((ext_vector_type(4))) float f32x4;

#define LOG2E 1.4426950408889634f
#define SCALE2 0.18033688011112042f  // 0.125 * log2(e)

__device__ __forceinline__ u16 f2b(float f) {  // RNE fp32->bf16
  union { float f; unsigned u; } v; v.f = f;
  unsigned r = v.u + 0x7fffu + ((v.u >> 16) & 1u);
  return (u16)(r >> 16);
}

// Raw workgroup barrier: seals LDS ops (lgkmcnt 0) without forcing vmcnt drain.
__device__ __forceinline__ void wg_barrier() {
  asm volatile("s_waitcnt lgkmcnt(0)\n\ts_barrier" ::: "memory");
}

// ---------------- merged prep: weight pack | rope table | mask transform | layernorm ----------------
__global__ __launch_bounds__(256) void prep(const float* __restrict__ w_qkv, u16* __restrict__ wqkv_b,
                                            const float* __restrict__ in_w, u16* __restrict__ inw_b,
                                            const float* __restrict__ out_w, u16* __restrict__ outw_b,
                                            float2* __restrict__ rtab,
                                            const float* __restrict__ mask, u16* __restrict__ maskp,
                                            const float* __restrict__ x,
                                            const float* __restrict__ ln_g,
                                            const float* __restrict__ ln_b,
                                            u16* __restrict__ xn) {
  __shared__ u16 T[128 * 68];
  __shared__ float sbuf[4], ssbuf[4];
  int blk = blockIdx.x, t = threadIdx.x;
  if (blk < 7168) {            // ---- fp32 -> bf16 weight pack
    int i = blk * 256 + t;
    const float* s; u16* d; int off;
    if (i < 786432)       { s = w_qkv; d = wqkv_b; off = i; }
    else if (i < 1572864) { s = in_w;  d = inw_b;  off = i - 786432; }
    else                  { s = out_w; d = outw_b; off = i - 1572864; }
    float4 v = ((const float4*)s)[off];
    uint2 o;
    o.x = (unsigned)f2b(v.x) | ((unsigned)f2b(v.y) << 16);
    o.y = (unsigned)f2b(v.z) | ((unsigned)f2b(v.w) << 16);
    ((uint2*)d)[off] = o;
  } else if (blk < 11264) {    // ---- RoPE cos/sin table
    int idx = (blk - 7168) * 256 + t;   // 1048576
    int pos = idx >> 9, i = idx & 511;
    float ifreq = exp2f(-(float)(2 * i) * (13.287712379549449f / 1024.0f));
    float ang = (float)pos * ifreq;
    rtab[idx] = make_float2(__cosf(ang), __sinf(ang));
  } else if (blk < 12288) {    // ---- mask -> bf16*log2e in S^T fragment order
    int mb = blk - 11264;      // 0..1023
    int kt = mb & 31, qt = (mb >> 5) & 15, bb = mb >> 9;
    const float* src = mask + ((size_t)bb * 2048 + qt * 128) * 2048 + kt * 64;
    #pragma unroll
    for (int it = 0; it < 8; it++) {
      int id = it * 256 + t;            // 0..2047 float4 groups (128 x 16)
      int r = id >> 4, c4 = (id & 15) * 4;
      float4 v = *(const float4*)(src + (size_t)r * 2048 + c4);
      T[r * 68 + c4 + 0] = f2b(v.x * LOG2E);
      T[r * 68 + c4 + 1] = f2b(v.y * LOG2E);
      T[r * 68 + c4 + 2] = f2b(v.z * LOG2E);
      T[r * 68 + c4 + 3] = f2b(v.w * LOG2E);
    }
    __syncthreads();
    size_t obase = (size_t)(((bb * 16 + qt) * 32) + kt) * 8192;
    #pragma unroll
    for (int it = 0; it < 2; it++) {
      int pos = it * 256 + t;           // 0..511
      int l15 = pos & 15, g = pos >> 4;
      int w = g >> 3, p = (g >> 2) & 1, qd = g & 3;
      int qlocal = w * 32 + p * 16 + l15;
      u16 vals[16];
      #pragma unroll
      for (int mt = 0; mt < 4; mt++)
        #pragma unroll
        for (int reg = 0; reg < 4; reg++)
          vals[mt * 4 + reg] = T[qlocal * 68 + mt * 16 + qd * 4 + reg];
      uint4* dst = (uint4*)(maskp + obase + (size_t)pos * 16);
      dst[0] = *(uint4*)&vals[0];
      dst[1] = *(uint4*)&vals[8];
    }
  } else {                     // ---- LayerNorm rows 0..4095 -> bf16
    int row = blk - 12288;
    const float* xr = x + (size_t)row * 1024;
    float4 v = *(const float4*)(xr + t * 4);
    float s = v.x + v.y + v.z + v.w;
    float ss = v.x * v.x + v.y * v.y + v.z * v.z + v.w * v.w;
    #pragma unroll
    for (int m = 1; m < 64; m <<= 1) {
      s  += __shfl_xor(s, m);
      ss += __shfl_xor(ss, m);
    }
    int wave = t >> 6, lane = t & 63;
    if (lane == 0) { sbuf[wave] = s; ssbuf[wave] = ss; }
    __syncthreads();
    s  = sbuf[0] + sbuf[1] + sbuf[2] + sbuf[3];
    ss = ssbuf[0] + ssbuf[1] + ssbuf[2] + ssbuf[3];
    float mean = s * (1.0f / 1024.0f);
    float var  = ss * (1.0f / 1024.0f) - mean * mean;
    float rstd = 1.0f / sqrtf(var + 1e-5f);
    float4 gv = *(const float4*)(ln_g + t * 4);
    float4 bv = *(const float4*)(ln_b + t * 4);
    uint2 o;
    o.x = (unsigned)f2b((v.x - mean) * rstd * gv.x + bv.x) |
          ((unsigned)f2b((v.y - mean) * rstd * gv.y + bv.y) << 16);
    o.y = (unsigned)f2b((v.z - mean) * rstd * gv.z + bv.z) |
          ((unsigned)f2b((v.w - mean) * rstd * gv.w + bv.w) << 16);
    *(uint2*)(xn + (size_t)row * 1024 + t * 4) = o;
  }
}

// ======== GEMM: BK=32, dbuf stride-36 LDS (3 blocks/CU), DISTANCE-3 two-set
// scalar-VGPR pipeline (tile loaded at iter k, stored at iter k+2), raw barrier.
// WVT: v-columns (col>=2048, SLAB) written transposed to vT instead of C. ========
template<bool SLAB, bool OUT_BF16, bool ROPE, bool WVT>
__global__ __launch_bounds__(256, 3) void gemm_pipe(const u16* __restrict__ A, int lda,
                                                    const u16* __restrict__ W,
                                                    const float* __restrict__ bias,
                                                    const float2* __restrict__ rtab,
                                                    float* __restrict__ Cf,
                                                    u16* __restrict__ Cb,
                                                    u16* __restrict__ vT,
                                                    int ldc, int K) {
  __shared__ u16 As[2][128 * 36];
  __shared__ u16 Bs[2][128 * 36];
  int n0 = blockIdx.x * 128, m0 = blockIdx.y * 128;
  int aoff = SLAB ? ((n0 >> 10) << 10) : 0;
  int tid = threadIdx.x;
  int lane = tid & 63, l15 = lane & 15, quad = lane >> 4;
  int w = tid >> 6, mw = w & 1, nw = w >> 1;
  const u16* Abase = A + (size_t)m0 * lda + aoff;
  const u16* Wbase = W + (size_t)n0 * K;
  int r0 = tid >> 2;              // 0..63
  int c4 = (tid & 3) * 8;         // col within 32-wide tile
  f32x4 acc[4][4];
  #pragma unroll
  for (int i = 0; i < 4; i++)
    #pragma unroll
    for (int j = 0; j < 4; j++) acc[i][j] = (f32x4){0.f, 0.f, 0.f, 0.f};

  uint4 a0, a1, w0, w1;       // prefetch set A
  uint4 b0, b1, x0, x1;       // prefetch set B
  #define GLOADS_A(k0)                                                        \
    a0 = *(const uint4*)(Abase + (size_t)(r0)      * lda + (k0) + c4);        \
    a1 = *(const uint4*)(Abase + (size_t)(r0 + 64) * lda + (k0) + c4);        \
    w0 = *(const uint4*)(Wbase + (size_t)(r0)      * K   + (k0) + c4);        \
    w1 = *(const uint4*)(Wbase + (size_t)(r0 + 64) * K   + (k0) + c4);
  #define GLOADS_B(k0)                                                        \
    b0 = *(const uint4*)(Abase + (size_t)(r0)      * lda + (k0) + c4);        \
    b1 = *(const uint4*)(Abase + (size_t)(r0 + 64) * lda + (k0) + c4);        \
    x0 = *(const uint4*)(Wbase + (size_t)(r0)      * K   + (k0) + c4);        \
    x1 = *(const uint4*)(Wbase + (size_t)(r0 + 64) * K   + (k0) + c4);
  #define LSTORES_A(bf)                                                       \
    *(uint4*)&As[bf][(r0)      * 36 + c4] = a0;                               \
    *(uint4*)&As[bf][(r0 + 64) * 36 + c4] = a1;                               \
    *(uint4*)&Bs[bf][(r0)      * 36 + c4] = w0;                               \
    *(uint4*)&Bs[bf][(r0 + 64) * 36 + c4] = w1;
  #define LSTORES_B(bf)                                                       \
    *(uint4*)&As[bf][(r0)      * 36 + c4] = b0;                               \
    *(uint4*)&As[bf][(r0 + 64) * 36 + c4] = b1;                               \
    *(uint4*)&Bs[bf][(r0)      * 36 + c4] = x0;                               \
    *(uint4*)&Bs[bf][(r0 + 64) * 36 + c4] = x1;
  #define COMPUTE(bf)                                                         \
    {                                                                         \
      short8 af[4], bfr[4];                                                   \
      _Pragma("unroll")                                                       \
      for (int mt = 0; mt < 4; mt++)                                          \
        af[mt] = *(const short8*)&As[bf][(mw * 64 + mt * 16 + l15) * 36 + quad * 8]; \
      _Pragma("unroll")                                                       \
      for (int nt = 0; nt < 4; nt++)                                          \
        bfr[nt] = *(const short8*)&Bs[bf][(nw * 64 + nt * 16 + l15) * 36 + quad * 8]; \
      _Pragma("unroll")                                                       \
      for (int mt = 0; mt < 4; mt++)                                          \
        _Pragma("unroll")                                                     \
        for (int nt = 0; nt < 4; nt++)                                        \
          acc[mt][nt] = __builtin_amdgcn_mfma_f32_16x16x32_bf16(              \
              af[mt], bfr[nt], acc[mt][nt], 0, 0, 0);                         \
    }

  GLOADS_A(0);
  LSTORES_A(0);               // tile 0 -> buf 0
  GLOADS_A(32);               // tile 1 -> set A
  GLOADS_B(64);               // tile 2 -> set B
  wg_barrier();
  for (int k0 = 0; k0 < K; k0 += 64) {
    // even iter (buf 0): store tile k+1 (set A), load tile k+3 into set A
    if (k0 + 32 < K)  { LSTORES_A(1); }
    if (k0 + 96 < K)  { GLOADS_A(k0 + 96); }
    COMPUTE(0);
    wg_barrier();
    // odd iter (buf 1): store tile k+2 (set B), load tile k+4 into set B
    if (k0 + 64 < K)  { LSTORES_B(0); }
    if (k0 + 128 < K) { GLOADS_B(k0 + 128); }
    COMPUTE(1);
    wg_barrier();
  }
  #undef GLOADS_A
  #undef GLOADS_B
  #undef LSTORES_A
  #undef LSTORES_B
  #undef COMPUTE
  int mb = m0 + mw * 64, nb = n0 + nw * 64;
  float bv[4];
  #pragma unroll
  for (int nt = 0; nt < 4; nt++) bv[nt] = bias[nb + nt * 16 + l15];
  #pragma unroll
  for (int mt = 0; mt < 4; mt++)
    #pragma unroll
    for (int nt = 0; nt < 4; nt++) {
      int col = nb + nt * 16 + l15;
      if (WVT && col >= 2048) {
        // v-columns: write transposed to vT[bb][h][d][s] (4 consecutive s per lane)
        int hh = (col - 2048) >> 6, dd = (col - 2048) & 63;
        int row0 = mb + mt * 16 + quad * 4;
        int bbi = row0 >> 11, s0 = row0 & 2047;
        u16 vv[4];
        #pragma unroll
        for (int reg = 0; reg < 4; reg++) vv[reg] = f2b(acc[mt][nt][reg] + bv[nt]);
        *(uint2*)&vT[((size_t)((bbi * 16 + hh) * 64 + dd)) * 2048 + s0] = *(uint2*)vv;
      } else {
        #pragma unroll
        for (int reg = 0; reg < 4; reg++) {
          int row = mb + mt * 16 + quad * 4 + reg;   // C/D: row=quad*4+reg, col=l15
          float val = acc[mt][nt][reg] + bv[nt];
          if (ROPE && col < 2048) {
            float pr = __shfl_xor(val, 1);
            float2 cs = rtab[(size_t)(row & 2047) * 512 + ((col & 1023) >> 1)];
            val = (col & 1) ? fmaf(val, cs.x, pr * cs.y)
                            : fmaf(val, cs.x, -pr * cs.y);
          }
          if (OUT_BF16) Cb[(size_t)row * ldc + col] = f2b(val);
          else          Cf[(size_t)row * ldc + col] = val;
        }
      }
    }
}

// ---------------- Flash attention: MQ=128, S^T formulation, raw barrier ----------------
__global__ __launch_bounds__(256) void attn_mfma(const u16* __restrict__ qkv2,
                                                 const u16* __restrict__ vT,
                                                 const u16* __restrict__ maskp,
                                                 u16* __restrict__ attn_out) {
  __shared__ u16 Kb[2][64 * 72];
  __shared__ u16 Vb[2][64 * 72];
  __shared__ u16 Ps[128 * 72];
  int h = blockIdx.x, qt = blockIdx.y, bb = blockIdx.z;
  int tid = threadIdx.x;
  int lane = tid & 63, l15 = lane & 15, quad = lane >> 4;
  int w = tid >> 6;
  int sr = tid >> 2, sc = (tid & 3) * 16;   // K/V staging decomposition (64x64 tile)
  const u16* kslab = qkv2 + ((size_t)bb * 2048) * 3072 + 1024 + h * 64;
  const u16* vslab = vT + ((size_t)((bb * 16 + h) * 64)) * 2048;

  {  // stage Q into wave-local Ps rows [w*32, w*32+32)
    int r = w * 32 + (lane >> 1), c0 = (lane & 1) * 32;
    const u16* src = qkv2 + (size_t)(bb * 2048 + qt * 128 + r) * 3072 + h * 64 + c0;
    #pragma unroll
    for (int u = 0; u < 4; u++)
      *(uint4*)&Ps[r * 72 + c0 + u * 8] = *(const uint4*)(src + u * 8);
  }
  {  // stage K/V tile 0
    const u16* ks = kslab + (size_t)sr * 3072 + sc;
    const u16* vs = vslab + (size_t)sr * 2048 + sc;
    *(uint4*)&Kb[0][sr * 72 + sc]     = *(const uint4*)ks;
    *(uint4*)&Kb[0][sr * 72 + sc + 8] = *(const uint4*)(ks + 8);
    *(uint4*)&Vb[0][sr * 72 + sc]     = *(const uint4*)vs;
    *(uint4*)&Vb[0][sr * 72 + sc + 8] = *(const uint4*)(vs + 8);
  }
  short8 bq[2][2];
  #pragma unroll
  for (int p = 0; p < 2; p++)
    #pragma unroll
    for (int hk = 0; hk < 2; hk++)
      bq[p][hk] = *(const short8*)&Ps[(w * 32 + p * 16 + l15) * 72 + hk * 32 + quad * 8];
  float lsum[2] = {0.f, 0.f};
  f32x4 acc[2][4];
  #pragma unroll
  for (int p = 0; p < 2; p++)
    #pragma unroll
    for (int dt = 0; dt < 4; dt++) acc[p][dt] = (f32x4){0.f, 0.f, 0.f, 0.f};
  const u16* mtile = maskp + ((size_t)((bb * 16 + qt) * 32)) * 8192
                     + (((w * 2) * 4 + quad) * 16 + l15) * 16;
  wg_barrier();

  for (int kt = 0; kt < 32; kt++) {
    int b = kt & 1;
    uint4 mA[2], mB[2];
    {
      const u16* mt_ = mtile + (size_t)kt * 8192;
      #pragma unroll
      for (int p = 0; p < 2; p++) {
        const uint4* mq = (const uint4*)(mt_ + p * 1024);
        mA[p] = mq[0]; mB[p] = mq[1];
      }
    }
    uint4 kr0, kr1, vr0, vr1;
    if (kt + 1 < 32) {
      const u16* ks = kslab + (size_t)((kt + 1) * 64 + sr) * 3072 + sc;
      const u16* vs = vslab + (size_t)sr * 2048 + (kt + 1) * 64 + sc;
      kr0 = *(const uint4*)ks; kr1 = *(const uint4*)(ks + 8);
      vr0 = *(const uint4*)vs; vr1 = *(const uint4*)(vs + 8);
    }
    short8 ak[4][2];
    #pragma unroll
    for (int mt = 0; mt < 4; mt++)
      #pragma unroll
      for (int hk = 0; hk < 2; hk++)
        ak[mt][hk] = *(const short8*)&Kb[b][(mt * 16 + l15) * 72 + hk * 32 + quad * 8];
    #pragma unroll
    for (int p = 0; p < 2; p++) {
      f32x4 st[4];
      #pragma unroll
      for (int mt = 0; mt < 4; mt++) {
        f32x4 z = (f32x4){0.f, 0.f, 0.f, 0.f};
        z = __builtin_amdgcn_mfma_f32_16x16x32_bf16(ak[mt][0], bq[p][0], z, 0, 0, 0);
        st[mt] = __builtin_amdgcn_mfma_f32_16x16x32_bf16(ak[mt][1], bq[p][1], z, 0, 0, 0);
      }
      u32 wds[8] = {mA[p].x, mA[p].y, mA[p].z, mA[p].w, mB[p].x, mB[p].y, mB[p].z, mB[p].w};
      float mv[16];
      #pragma unroll
      for (int j = 0; j < 8; j++) {
        mv[2 * j]     = __uint_as_float(wds[j] << 16);
        mv[2 * j + 1] = __uint_as_float(wds[j] & 0xffff0000u);
      }
      int prow = (w * 32 + p * 16 + l15) * 72 + quad * 4;
      #pragma unroll
      for (int mt = 0; mt < 4; mt++) {
        u32 pk0, pk1;
        float sv0 = fmaf(st[mt][0], SCALE2, mv[mt * 4 + 0]);
        float sv1 = fmaf(st[mt][1], SCALE2, mv[mt * 4 + 1]);
        float sv2 = fmaf(st[mt][2], SCALE2, mv[mt * 4 + 2]);
        float sv3 = fmaf(st[mt][3], SCALE2, mv[mt * 4 + 3]);
        float p0 = __builtin_amdgcn_exp2f(sv0), p1 = __builtin_amdgcn_exp2f(sv1);
        float p2 = __builtin_amdgcn_exp2f(sv2), p3 = __builtin_amdgcn_exp2f(sv3);
        lsum[p] += (p0 + p1) + (p2 + p3);
        pk0 = ((__float_as_uint(p0) + 0x8000u) >> 16) |
              ((__float_as_uint(p1) + 0x8000u) & 0xffff0000u);
        pk1 = ((__float_as_uint(p2) + 0x8000u) >> 16) |
              ((__float_as_uint(p3) + 0x8000u) & 0xffff0000u);
        *(uint2*)&Ps[prow + mt * 16] = make_uint2(pk0, pk1);
      }
    }
    short8 ap[2][2];
    #pragma unroll
    for (int p = 0; p < 2; p++)
      #pragma unroll
      for (int hk = 0; hk < 2; hk++)
        ap[p][hk] = *(const short8*)&Ps[(w * 32 + p * 16 + l15) * 72 + hk * 32 + quad * 8];
    #pragma unroll
    for (int dt = 0; dt < 4; dt++) {
      short8 bv0 = *(const short8*)&Vb[b][(dt * 16 + l15) * 72 + quad * 8];
      short8 bv1 = *(const short8*)&Vb[b][(dt * 16 + l15) * 72 + 32 + quad * 8];
      #pragma unroll
      for (int p = 0; p < 2; p++) {
        acc[p][dt] = __builtin_amdgcn_mfma_f32_16x16x32_bf16(ap[p][0], bv0, acc[p][dt], 0, 0, 0);
        acc[p][dt] = __builtin_amdgcn_mfma_f32_16x16x32_bf16(ap[p][1], bv1, acc[p][dt], 0, 0, 0);
      }
    }
    if (kt + 1 < 32) {
      int nb = b ^ 1;
      *(uint4*)&Kb[nb][sr * 72 + sc]     = kr0;
      *(uint4*)&Kb[nb][sr * 72 + sc + 8] = kr1;
      *(uint4*)&Vb[nb][sr * 72 + sc]     = vr0;
      *(uint4*)&Vb[nb][sr * 72 + sc + 8] = vr1;
    }
    wg_barrier();
  }
  #pragma unroll
  for (int p = 0; p < 2; p++) {
    float l = lsum[p];
    l += __shfl_xor(l, 16);
    l += __shfl_xor(l, 32);
    #pragma unroll
    for (int reg = 0; reg < 4; reg++) {
      float lq = __shfl(l, quad * 4 + reg);
      float inv = 1.0f / lq;
      int grow = bb * 2048 + qt * 128 + w * 32 + p * 16 + quad * 4 + reg;
      #pragma unroll
      for (int dt = 0; dt < 4; dt++)
        attn_out[(size_t)grow * 1024 + h * 64 + dt * 16 + l15] = f2b(acc[p][dt][reg] * inv);
    }
  }
}

extern "C" void kernel_launch(void* const* d_in, const int* in_sizes, int n_in,
                              void* d_out, int out_size, void* d_ws, size_t ws_size,
                              hipStream_t stream) {
  const float* x     = (const float*)d_in[0];
  const float* mask  = (const float*)d_in[1];
  const float* ln_g  = (const float*)d_in[2];
  const float* ln_b  = (const float*)d_in[3];
  const float* w_qkv = (const float*)d_in[4];
  const float* b_qkv = (const float*)d_in[5];
  const float* in_w  = (const float*)d_in[6];
  const float* in_b  = (const float*)d_in[7];
  const float* out_w = (const float*)d_in[8];
  const float* out_b = (const float*)d_in[9];
  float* out = (float*)d_out;
  char* ws = (char*)d_ws;

  u16* wqkv_b = (u16*)(ws);                   //  6291456  (3072x1024)
  u16* inw_b  = (u16*)(ws + 6291456ull);      //  6291456  (3072x1024)
  u16* outw_b = (u16*)(ws + 12582912ull);     //  2097152  (1024x1024)
  u16* xn_b   = (u16*)(ws + 14680064ull);     //  8388608  (4096x1024)
  u16* attn_b = xn_b;                         //  reuse (xn dead after gemm1)
  u16* qkv_b  = (u16*)(ws + 23068672ull);     // 25165824  (4096x3072)
  u16* qkv2_b = (u16*)(ws + 48234496ull);     // 25165824  (4096x3072; v cols unused)
  float2* rtab = (float2*)qkv2_b;             //  8388608  aliases qkv2 (dead before gemm2)
  u16* vT     = (u16*)(ws + 73400320ull);     //  8388608  (2,16,64,2048)
  u16* maskp  = (u16*)(ws + 81788928ull);     // 16777216  (2*16*32 tiles * 8192 u16)

  prep<<<16384, 256, 0, stream>>>(w_qkv, wqkv_b, in_w, inw_b, out_w, outw_b,
                                  rtab, mask, maskp, x, ln_g, ln_b, xn_b);
  gemm_pipe<false, true, true, false><<<dim3(24, 32), 256, 0, stream>>>(
      xn_b, 1024, wqkv_b, b_qkv, rtab, nullptr, qkv_b, nullptr, 3072, 1024);
  gemm_pipe<true, true, false, true><<<dim3(24, 32), 256, 0, stream>>>(
      qkv_b, 3072, inw_b, in_b, nullptr, nullptr, qkv2_b, vT, 3072, 1024);
  attn_mfma<<<dim3(16, 16, 2), 256, 0, stream>>>(qkv2_b, vT, maskp, attn_b);
  gemm_pipe<false, false, false, false><<<dim3(8, 32), 256, 0, stream>>>(
      attn_b, 1024, outw_b, out_b, nullptr, out, nullptr, nullptr, 1024, 1024);
}